// Round 4
// baseline (679.009 us; speedup 1.0000x reference)
//
#include <hip/hip_runtime.h>
#include <hip/hip_bf16.h>

#define DHID 128
#define NH 12
#define KDIM 1536   // NH * DHID

typedef __attribute__((ext_vector_type(8))) short short8;
typedef __attribute__((ext_vector_type(4))) float f32x4;

static __device__ __forceinline__ unsigned short f2bf(float f) {
  __hip_bfloat16 h = __float2bfloat16(f);
  return __builtin_bit_cast(unsigned short, h);
}

// ---------------- sort (counting sort of edges by dst) ----------------

__global__ void hist_k(const int* __restrict__ dstp, int* __restrict__ cnt, int e0, int et) {
  int e = blockIdx.x * blockDim.x + threadIdx.x;
  if (e >= et) return;
  int d = (e < e0) ? dstp[e] : (e - e0);   // self-loop edges appended at the end
  atomicAdd(&cnt[d], 1);
}

// cnt and cursor may alias (in-place): each element is read before rewrite.
__global__ void scan_k(const int* __restrict__ cnt, int* __restrict__ row_start,
                       int* __restrict__ cursor, int n, int total) {
  __shared__ int part[1024];
  int t = threadIdx.x;
  const int CH = (n + 1023) >> 10;
  int base = t * CH;
  int s = 0;
  for (int j = 0; j < CH; ++j) { int i = base + j; if (i < n) s += cnt[i]; }
  part[t] = s;
  __syncthreads();
  for (int off = 1; off < 1024; off <<= 1) {
    int v = (t >= off) ? part[t - off] : 0;
    __syncthreads();
    part[t] += v;
    __syncthreads();
  }
  int run = (t == 0) ? 0 : part[t - 1];
  for (int j = 0; j < CH; ++j) {
    int i = base + j;
    if (i < n) {
      int c = cnt[i];              // read BEFORE cursor write (may alias)
      row_start[i] = run;
      cursor[i] = run;
      run += c;
    }
  }
  if (t == 0) row_start[n] = total;
}

__global__ void scatter_k(const int* __restrict__ srcp, const int* __restrict__ dstp,
                          int* __restrict__ cursor, int* __restrict__ srcs,
                          int* __restrict__ dsts, int e0, int et) {
  int e = blockIdx.x * blockDim.x + threadIdx.x;
  if (e >= et) return;
  int s = (e < e0) ? srcp[e] : (e - e0);
  int d = (e < e0) ? dstp[e] : (e - e0);
  int pos = atomicAdd(&cursor[d], 1);
  srcs[pos] = s;
  dsts[pos] = d;
}

// ---------------- per-node u = x . Wu[h] ----------------

__global__ void u_k(const float* __restrict__ x, const float* __restrict__ Wu,
                    float* __restrict__ u, int n) {
  int wid = (blockIdx.x * blockDim.x + threadIdx.x) >> 6;
  if (wid >= n) return;
  int lane = threadIdx.x & 63;
  float2 xv = *(const float2*)(x + (long)wid * DHID + 2 * lane);
  #pragma unroll
  for (int h = 0; h < NH; ++h) {
    float2 wv = *(const float2*)(Wu + h * DHID + 2 * lane);
    float p = xv.x * wv.x + xv.y * wv.y;
    p += __shfl_xor(p, 1);  p += __shfl_xor(p, 2);  p += __shfl_xor(p, 4);
    p += __shfl_xor(p, 8);  p += __shfl_xor(p, 16); p += __shfl_xor(p, 32);
    if (lane == 0) u[wid * NH + h] = p;
  }
}

// ---------------- per-edge attention (thread per edge, dst-sorted order) ----------------
// attS[j][h] = softmax_h(u[dst]-u[src]+c) / deg(dst)

__global__ void att_k(const float* __restrict__ u, const float* __restrict__ cvec,
                      const int* __restrict__ srcs, const int* __restrict__ dsts,
                      const int* __restrict__ row_start, float* __restrict__ attS, int et) {
  int j = blockIdx.x * blockDim.x + threadIdx.x;
  if (j >= et) return;
  int s = srcs[j], d = dsts[j];
  const float4* ud = (const float4*)(u + (long)d * NH);
  const float4* us = (const float4*)(u + (long)s * NH);
  const float4* cp = (const float4*)cvec;
  float w[NH];
  #pragma unroll
  for (int q = 0; q < 3; ++q) {
    float4 a = ud[q], b = us[q], c = cp[q];
    w[4*q+0] = a.x - b.x + c.x;
    w[4*q+1] = a.y - b.y + c.y;
    w[4*q+2] = a.z - b.z + c.z;
    w[4*q+3] = a.w - b.w + c.w;
  }
  float m = w[0];
  #pragma unroll
  for (int h = 1; h < NH; ++h) m = fmaxf(m, w[h]);
  float ssum = 0.f;
  #pragma unroll
  for (int h = 0; h < NH; ++h) { w[h] = __expf(w[h] - m); ssum += w[h]; }
  float deg = (float)(row_start[d + 1] - row_start[d]);
  float inv = 1.f / (ssum * deg);
  float4* op = (float4*)(attS + (long)j * NH);
  #pragma unroll
  for (int q = 0; q < 3; ++q) {
    float4 v;
    v.x = w[4*q+0] * inv; v.y = w[4*q+1] * inv;
    v.z = w[4*q+2] * inv; v.w = w[4*q+3] * inv;
    op[q] = v;
  }
}

// ---------------- edge aggregation: A[n,h,:] = sum_j attS[j,h] * x[srcs[j]] ----------------

__global__ void edge_k(const float* __restrict__ x, const float* __restrict__ attS,
                       const int* __restrict__ srcs, const int* __restrict__ row_start,
                       unsigned short* __restrict__ A, int n) {
  int wid = __builtin_amdgcn_readfirstlane((int)((blockIdx.x * blockDim.x + threadIdx.x) >> 6));
  if (wid >= n) return;
  int lane = threadIdx.x & 63;
  float acc[NH][2];
  #pragma unroll
  for (int h = 0; h < NH; ++h) { acc[h][0] = 0.f; acc[h][1] = 0.f; }
  int beg = row_start[wid], end = row_start[wid + 1];
  int j = beg;
  for (; j + 1 < end; j += 2) {
    int s0 = srcs[j], s1 = srcs[j + 1];
    float2 xv0 = *(const float2*)(x + (long)s0 * DHID + 2 * lane);
    float2 xv1 = *(const float2*)(x + (long)s1 * DHID + 2 * lane);
    const float4* a0p = (const float4*)(attS + (long)j * NH);
    float4 a00 = a0p[0], a01 = a0p[1], a02 = a0p[2];
    float4 a10 = a0p[3], a11 = a0p[4], a12 = a0p[5];
    float av0[NH], av1[NH];
    av0[0]=a00.x; av0[1]=a00.y; av0[2]=a00.z;  av0[3]=a00.w;
    av0[4]=a01.x; av0[5]=a01.y; av0[6]=a01.z;  av0[7]=a01.w;
    av0[8]=a02.x; av0[9]=a02.y; av0[10]=a02.z; av0[11]=a02.w;
    av1[0]=a10.x; av1[1]=a10.y; av1[2]=a10.z;  av1[3]=a10.w;
    av1[4]=a11.x; av1[5]=a11.y; av1[6]=a11.z;  av1[7]=a11.w;
    av1[8]=a12.x; av1[9]=a12.y; av1[10]=a12.z; av1[11]=a12.w;
    #pragma unroll
    for (int h = 0; h < NH; ++h) {
      acc[h][0] += av0[h] * xv0.x + av1[h] * xv1.x;
      acc[h][1] += av0[h] * xv0.y + av1[h] * xv1.y;
    }
  }
  if (j < end) {
    int s0 = srcs[j];
    float2 xv0 = *(const float2*)(x + (long)s0 * DHID + 2 * lane);
    const float4* a0p = (const float4*)(attS + (long)j * NH);
    float4 a00 = a0p[0], a01 = a0p[1], a02 = a0p[2];
    float av0[NH];
    av0[0]=a00.x; av0[1]=a00.y; av0[2]=a00.z;  av0[3]=a00.w;
    av0[4]=a01.x; av0[5]=a01.y; av0[6]=a01.z;  av0[7]=a01.w;
    av0[8]=a02.x; av0[9]=a02.y; av0[10]=a02.z; av0[11]=a02.w;
    #pragma unroll
    for (int h = 0; h < NH; ++h) {
      acc[h][0] += av0[h] * xv0.x;
      acc[h][1] += av0[h] * xv0.y;
    }
  }
  unsigned* Ap = (unsigned*)(A + (long)wid * KDIM);
  #pragma unroll
  for (int h = 0; h < NH; ++h) {
    unsigned pv = (unsigned)f2bf(acc[h][0]) | ((unsigned)f2bf(acc[h][1]) << 16);
    Ap[h * (DHID / 2) + lane] = pv;
  }
}

// ---------------- weight repack: Wcat[c][h*128+k] = Wlin[h*128+c][k], bf16 ----------------

__global__ void prep_wcat_k(const float* __restrict__ Wlin, unsigned short* __restrict__ Wcat) {
  int t = blockIdx.x * blockDim.x + threadIdx.x;  // 128*1536 total
  int c = t / KDIM, f = t - c * KDIM;
  int h = f >> 7, k = f & (DHID - 1);
  Wcat[t] = f2bf(Wlin[((h << 7) + c) * DHID + k]);
}

// ---------------- GEMM: part[ks][m,c] = A[m, ks-half] . Wcat[c, ks-half] ----------------
// 32 rows x 128 cols per block (4 waves, each 32x32), split-K 2 -> 1250 blocks.

__global__ __launch_bounds__(256) void gemm_k(
    const unsigned short* __restrict__ A, const unsigned short* __restrict__ B,
    float* __restrict__ part, int M) {
  int w = threadIdx.x >> 6, lane = threadIdx.x & 63;
  int lr = lane & 15, lq = lane >> 4;
  int m0 = blockIdx.x * 32, n0 = w * 32;
  int ks = blockIdx.y;
  if (m0 >= M) return;
  f32x4 acc[2][2];
  #pragma unroll
  for (int mf = 0; mf < 2; ++mf)
    #pragma unroll
    for (int nf = 0; nf < 2; ++nf) acc[mf][nf] = (f32x4){0.f, 0.f, 0.f, 0.f};
  const short* Ap = (const short*)A;
  const short* Bp = (const short*)B;
  long arow0 = (long)(m0 + lr) * KDIM + lq * 8;
  long arow1 = (long)(m0 + 16 + lr) * KDIM + lq * 8;
  long brow0 = (long)(n0 + lr) * KDIM + lq * 8;
  long brow1 = (long)(n0 + 16 + lr) * KDIM + lq * 8;
  const int kbeg = ks * (KDIM / 2), kend = kbeg + (KDIM / 2);
  #pragma unroll 2
  for (int kk = kbeg; kk < kend; kk += 32) {
    short8 a0 = *(const short8*)(Ap + arow0 + kk);
    short8 a1 = *(const short8*)(Ap + arow1 + kk);
    short8 b0 = *(const short8*)(Bp + brow0 + kk);
    short8 b1 = *(const short8*)(Bp + brow1 + kk);
    acc[0][0] = __builtin_amdgcn_mfma_f32_16x16x32_bf16(a0, b0, acc[0][0], 0, 0, 0);
    acc[0][1] = __builtin_amdgcn_mfma_f32_16x16x32_bf16(a0, b1, acc[0][1], 0, 0, 0);
    acc[1][0] = __builtin_amdgcn_mfma_f32_16x16x32_bf16(a1, b0, acc[1][0], 0, 0, 0);
    acc[1][1] = __builtin_amdgcn_mfma_f32_16x16x32_bf16(a1, b1, acc[1][1], 0, 0, 0);
  }
  float* op = part + (long)ks * M * DHID;
  #pragma unroll
  for (int mf = 0; mf < 2; ++mf) {
    #pragma unroll
    for (int nf = 0; nf < 2; ++nf) {
      int c = n0 + nf * 16 + lr;
      int rowb = m0 + mf * 16 + lq * 4;
      #pragma unroll
      for (int r = 0; r < 4; ++r)
        op[(long)(rowb + r) * DHID + c] = acc[mf][nf][r];
    }
  }
}

// ---------------- combine partials: out = part0 + part1 + bias, relu, BN stats ----------------

__global__ void combine_k(const float* __restrict__ part, const float* __restrict__ bias,
                          float* __restrict__ outp, float* __restrict__ bnpart,
                          int M, int relu, int dobn) {
  int t = blockIdx.x * blockDim.x + threadIdx.x;
  int nvec = M * (DHID / 4);
  if (t >= nvec) return;
  long idx = (long)t * 4;
  int c = (int)(idx & (DHID - 1));     // = (t & 31) * 4
  float4 p0 = *(const float4*)(part + idx);
  float4 p1 = *(const float4*)(part + (long)M * DHID + idx);
  float4 bc = *(const float4*)(bias + c);
  float4 v;
  v.x = p0.x + p1.x + bc.x;
  v.y = p0.y + p1.y + bc.y;
  v.z = p0.z + p1.z + bc.z;
  v.w = p0.w + p1.w + bc.w;
  if (relu) {
    v.x = fmaxf(v.x, 0.f); v.y = fmaxf(v.y, 0.f);
    v.z = fmaxf(v.z, 0.f); v.w = fmaxf(v.w, 0.f);
  }
  *(float4*)(outp + idx) = v;
  if (dobn) {
    float4 q;
    q.x = v.x * v.x; q.y = v.y * v.y; q.z = v.z * v.z; q.w = v.w * v.w;
    // lanes l and l^32 hold the same 4 channels -> fold, then lanes 0..31 do atomics
    v.x += __shfl_xor(v.x, 32); v.y += __shfl_xor(v.y, 32);
    v.z += __shfl_xor(v.z, 32); v.w += __shfl_xor(v.w, 32);
    q.x += __shfl_xor(q.x, 32); q.y += __shfl_xor(q.y, 32);
    q.z += __shfl_xor(q.z, 32); q.w += __shfl_xor(q.w, 32);
    if ((threadIdx.x & 63) < 32) {
      float* bp = bnpart + (blockIdx.x & 31) * 256 + c;
      atomicAdd(&bp[0], v.x); atomicAdd(&bp[1], v.y);
      atomicAdd(&bp[2], v.z); atomicAdd(&bp[3], v.w);
      float* bq = bp + 128;
      atomicAdd(&bq[0], q.x); atomicAdd(&bq[1], q.y);
      atomicAdd(&bq[2], q.z); atomicAdd(&bq[3], q.w);
    }
  }
}

// ---------------- BatchNorm finalize + apply (in place) ----------------

__global__ void bnfin_k(const float* __restrict__ bnpart,
                        const float* __restrict__ g, const float* __restrict__ b,
                        float* __restrict__ sc, float* __restrict__ sh, float invn) {
  int c = threadIdx.x;
  float s = 0.f, q = 0.f;
  #pragma unroll
  for (int i = 0; i < 32; ++i) {
    s += bnpart[i * 256 + c];
    q += bnpart[i * 256 + 128 + c];
  }
  float m = s * invn;
  float v = q * invn - m * m;
  float rs = rsqrtf(v + 1e-5f);
  float sg = g[c] * rs;
  sc[c] = sg;
  sh[c] = b[c] - m * sg;
}

__global__ void bnapply_k(float* __restrict__ buf, const float* __restrict__ sc,
                          const float* __restrict__ sh, int nvec) {
  int i = blockIdx.x * blockDim.x + threadIdx.x;
  if (i >= nvec) return;
  long idx = (long)i * 4;
  int c = (int)(idx & (DHID - 1));
  float4 v = *(const float4*)(buf + idx);
  v.x = v.x * sc[c]     + sh[c];
  v.y = v.y * sc[c + 1] + sh[c + 1];
  v.z = v.z * sc[c + 2] + sh[c + 2];
  v.w = v.w * sc[c + 3] + sh[c + 3];
  *(float4*)(buf + idx) = v;
}

// ---------------- launch ----------------

extern "C" void kernel_launch(void* const* d_in, const int* in_sizes, int n_in,
                              void* d_out, int out_size, void* d_ws, size_t ws_size,
                              hipStream_t stream) {
  const float* x = (const float*)d_in[0];
  const int* ei = (const int*)d_in[1];
  const int N = in_sizes[0] / DHID;
  const int E0 = in_sizes[1] / 2;
  const int ET = E0 + N;
  const int* srcp = ei;
  const int* dstp = ei + E0;
  const float* Wlin[3] = {(const float*)d_in[2], (const float*)d_in[6], (const float*)d_in[10]};
  const float* Wu[3]   = {(const float*)d_in[3], (const float*)d_in[7], (const float*)d_in[11]};
  const float* cc[3]   = {(const float*)d_in[4], (const float*)d_in[8], (const float*)d_in[12]};
  const float* bb[3]   = {(const float*)d_in[5], (const float*)d_in[9], (const float*)d_in[13]};
  const float* bng[2]  = {(const float*)d_in[14], (const float*)d_in[16]};
  const float* bnb[2]  = {(const float*)d_in[15], (const float*)d_in[17]};

  const int MPAD = ((N + 31) / 32) * 32;

  // carve workspace
  size_t o = 0;
  char* base = (char*)d_ws;
  auto carve = [&](size_t bytes) -> char* {
    char* p = base + o;
    o += (bytes + 255) & ~(size_t)255;
    return p;
  };
  int* row_start = (int*)carve((size_t)(N + 1) * 4);
  int* cursor    = (int*)carve((size_t)N * 4);       // doubles as histogram
  int* srcs      = (int*)carve((size_t)ET * 4);
  int* dsts      = (int*)carve((size_t)ET * 4);
  float* u       = (float*)carve((size_t)N * NH * 4);
  float* bnpart  = (float*)carve((size_t)32 * 256 * 4);
  float* bnsc    = (float*)carve((size_t)DHID * 4);
  float* bnsh    = (float*)carve((size_t)DHID * 4);
  unsigned short* Wcat = (unsigned short*)carve((size_t)DHID * KDIM * 2);
  // attS and split-K partials alias (disjoint in time within a layer)
  size_t attS_bytes = (size_t)ET * NH * 4;
  size_t part_bytes = (size_t)2 * MPAD * DHID * 4;
  char* shared_rg = carve(attS_bytes > part_bytes ? attS_bytes : part_bytes);
  float* attS = (float*)shared_rg;
  float* partb = (float*)shared_rg;
  float* hA      = (float*)carve((size_t)N * DHID * 4);
  unsigned short* A = (unsigned short*)carve((size_t)MPAD * KDIM * 2);
  (void)ws_size; (void)n_in; (void)out_size;

  const int EB = (ET + 255) / 256;
  const int NW = (N + 3) / 4;       // 4 waves (nodes) per 256-thread block
  const int MB32 = (N + 31) / 32;
  const int AV = (N * DHID / 4 + 255) / 256;

  // sort edges by dst (once; dst list is layer-invariant)
  hipMemsetAsync(cursor, 0, (size_t)N * 4, stream);
  hist_k<<<EB, 256, 0, stream>>>(dstp, cursor, E0, ET);
  scan_k<<<1, 1024, 0, stream>>>(cursor, row_start, cursor, N, ET);
  scatter_k<<<EB, 256, 0, stream>>>(srcp, dstp, cursor, srcs, dsts, E0, ET);

  const float* hin = x;
  for (int li = 0; li < 3; ++li) {
    const bool last = (li == 2);
    u_k<<<NW, 256, 0, stream>>>(hin, Wu[li], u, N);
    att_k<<<EB, 256, 0, stream>>>(u, cc[li], srcs, dsts, row_start, attS, ET);
    edge_k<<<NW, 256, 0, stream>>>(hin, attS, srcs, row_start, A, N);
    prep_wcat_k<<<(DHID * KDIM) / 256, 256, 0, stream>>>(Wlin[li], Wcat);
    if (!last) hipMemsetAsync(bnpart, 0, (size_t)32 * 256 * 4, stream);
    gemm_k<<<dim3(MB32, 2), 256, 0, stream>>>(A, Wcat, partb, N);
    float* outp = last ? (float*)d_out : hA;
    combine_k<<<AV, 256, 0, stream>>>(partb, bb[li], outp, bnpart,
                                      N, last ? 0 : 1, last ? 0 : 1);
    if (!last) {
      bnfin_k<<<1, DHID, 0, stream>>>(bnpart, bng[li], bnb[li], bnsc, bnsh, 1.f / (float)N);
      bnapply_k<<<AV, 256, 0, stream>>>(hA, bnsc, bnsh, N * DHID / 4);
      hin = hA;
    }
  }
}

// Round 5
// 565.678 us; speedup vs baseline: 1.2003x; 1.2003x over previous
//
#include <hip/hip_runtime.h>
#include <hip/hip_bf16.h>

#define DHID 128
#define NH 12
#define KDIM 1536   // NH * DHID
#define NSTATB 128  // bnstat partial blocks

typedef __attribute__((ext_vector_type(8))) short short8;
typedef __attribute__((ext_vector_type(4))) float f32x4;

static __device__ __forceinline__ unsigned short f2bf(float f) {
  __hip_bfloat16 h = __float2bfloat16(f);
  return __builtin_bit_cast(unsigned short, h);
}

// ---------------- sort (counting sort of edges by dst) ----------------

__global__ void hist_k(const int* __restrict__ dstp, int* __restrict__ cnt, int e0, int et) {
  int e = blockIdx.x * blockDim.x + threadIdx.x;
  if (e >= et) return;
  int d = (e < e0) ? dstp[e] : (e - e0);   // self-loop edges appended at the end
  atomicAdd(&cnt[d], 1);
}

// cnt and cursor may alias (in-place): each element is read before rewrite.
__global__ void scan_k(const int* __restrict__ cnt, int* __restrict__ row_start,
                       int* __restrict__ cursor, int n, int total) {
  __shared__ int part[1024];
  int t = threadIdx.x;
  const int CH = (n + 1023) >> 10;
  int base = t * CH;
  int s = 0;
  for (int j = 0; j < CH; ++j) { int i = base + j; if (i < n) s += cnt[i]; }
  part[t] = s;
  __syncthreads();
  for (int off = 1; off < 1024; off <<= 1) {
    int v = (t >= off) ? part[t - off] : 0;
    __syncthreads();
    part[t] += v;
    __syncthreads();
  }
  int run = (t == 0) ? 0 : part[t - 1];
  for (int j = 0; j < CH; ++j) {
    int i = base + j;
    if (i < n) {
      int c = cnt[i];              // read BEFORE cursor write (may alias)
      row_start[i] = run;
      cursor[i] = run;
      run += c;
    }
  }
  if (t == 0) row_start[n] = total;
}

__global__ void scatter_k(const int* __restrict__ srcp, const int* __restrict__ dstp,
                          int* __restrict__ cursor, int* __restrict__ srcs,
                          int* __restrict__ dsts, int e0, int et) {
  int e = blockIdx.x * blockDim.x + threadIdx.x;
  if (e >= et) return;
  int s = (e < e0) ? srcp[e] : (e - e0);
  int d = (e < e0) ? dstp[e] : (e - e0);
  int pos = atomicAdd(&cursor[d], 1);
  srcs[pos] = s;
  dsts[pos] = d;
}

// ---------------- per-node u = x . Wu[h] ----------------

__global__ void u_k(const float* __restrict__ x, const float* __restrict__ Wu,
                    float* __restrict__ u, int n) {
  int wid = (blockIdx.x * blockDim.x + threadIdx.x) >> 6;
  if (wid >= n) return;
  int lane = threadIdx.x & 63;
  float2 xv = *(const float2*)(x + (long)wid * DHID + 2 * lane);
  #pragma unroll
  for (int h = 0; h < NH; ++h) {
    float2 wv = *(const float2*)(Wu + h * DHID + 2 * lane);
    float p = xv.x * wv.x + xv.y * wv.y;
    p += __shfl_xor(p, 1);  p += __shfl_xor(p, 2);  p += __shfl_xor(p, 4);
    p += __shfl_xor(p, 8);  p += __shfl_xor(p, 16); p += __shfl_xor(p, 32);
    if (lane == 0) u[wid * NH + h] = p;
  }
}

// ---------------- per-edge attention (thread per edge, dst-sorted order) ----------------
// attS[j][h] = softmax_h(u[dst]-u[src]+c) / deg(dst)

__global__ void att_k(const float* __restrict__ u, const float* __restrict__ cvec,
                      const int* __restrict__ srcs, const int* __restrict__ dsts,
                      const int* __restrict__ row_start, float* __restrict__ attS, int et) {
  int j = blockIdx.x * blockDim.x + threadIdx.x;
  if (j >= et) return;
  int s = srcs[j], d = dsts[j];
  const float4* ud = (const float4*)(u + (long)d * NH);
  const float4* us = (const float4*)(u + (long)s * NH);
  const float4* cp = (const float4*)cvec;
  float w[NH];
  #pragma unroll
  for (int q = 0; q < 3; ++q) {
    float4 a = ud[q], b = us[q], c = cp[q];
    w[4*q+0] = a.x - b.x + c.x;
    w[4*q+1] = a.y - b.y + c.y;
    w[4*q+2] = a.z - b.z + c.z;
    w[4*q+3] = a.w - b.w + c.w;
  }
  float m = w[0];
  #pragma unroll
  for (int h = 1; h < NH; ++h) m = fmaxf(m, w[h]);
  float ssum = 0.f;
  #pragma unroll
  for (int h = 0; h < NH; ++h) { w[h] = __expf(w[h] - m); ssum += w[h]; }
  float deg = (float)(row_start[d + 1] - row_start[d]);
  float inv = 1.f / (ssum * deg);
  float4* op = (float4*)(attS + (long)j * NH);
  #pragma unroll
  for (int q = 0; q < 3; ++q) {
    float4 v;
    v.x = w[4*q+0] * inv; v.y = w[4*q+1] * inv;
    v.z = w[4*q+2] * inv; v.w = w[4*q+3] * inv;
    op[q] = v;
  }
}

// ---------------- edge aggregation: A[n,h,:] = sum_j attS[j,h] * x[srcs[j]] ----------------

__global__ void edge_k(const float* __restrict__ x, const float* __restrict__ attS,
                       const int* __restrict__ srcs, const int* __restrict__ row_start,
                       unsigned short* __restrict__ A, int n) {
  int wid = __builtin_amdgcn_readfirstlane((int)((blockIdx.x * blockDim.x + threadIdx.x) >> 6));
  if (wid >= n) return;
  int lane = threadIdx.x & 63;
  float acc[NH][2];
  #pragma unroll
  for (int h = 0; h < NH; ++h) { acc[h][0] = 0.f; acc[h][1] = 0.f; }
  int beg = row_start[wid], end = row_start[wid + 1];
  int j = beg;
  for (; j + 1 < end; j += 2) {
    int s0 = srcs[j], s1 = srcs[j + 1];
    float2 xv0 = *(const float2*)(x + (long)s0 * DHID + 2 * lane);
    float2 xv1 = *(const float2*)(x + (long)s1 * DHID + 2 * lane);
    const float4* a0p = (const float4*)(attS + (long)j * NH);
    float4 a00 = a0p[0], a01 = a0p[1], a02 = a0p[2];
    float4 a10 = a0p[3], a11 = a0p[4], a12 = a0p[5];
    float av0[NH], av1[NH];
    av0[0]=a00.x; av0[1]=a00.y; av0[2]=a00.z;  av0[3]=a00.w;
    av0[4]=a01.x; av0[5]=a01.y; av0[6]=a01.z;  av0[7]=a01.w;
    av0[8]=a02.x; av0[9]=a02.y; av0[10]=a02.z; av0[11]=a02.w;
    av1[0]=a10.x; av1[1]=a10.y; av1[2]=a10.z;  av1[3]=a10.w;
    av1[4]=a11.x; av1[5]=a11.y; av1[6]=a11.z;  av1[7]=a11.w;
    av1[8]=a12.x; av1[9]=a12.y; av1[10]=a12.z; av1[11]=a12.w;
    #pragma unroll
    for (int h = 0; h < NH; ++h) {
      acc[h][0] += av0[h] * xv0.x + av1[h] * xv1.x;
      acc[h][1] += av0[h] * xv0.y + av1[h] * xv1.y;
    }
  }
  if (j < end) {
    int s0 = srcs[j];
    float2 xv0 = *(const float2*)(x + (long)s0 * DHID + 2 * lane);
    const float4* a0p = (const float4*)(attS + (long)j * NH);
    float4 a00 = a0p[0], a01 = a0p[1], a02 = a0p[2];
    float av0[NH];
    av0[0]=a00.x; av0[1]=a00.y; av0[2]=a00.z;  av0[3]=a00.w;
    av0[4]=a01.x; av0[5]=a01.y; av0[6]=a01.z;  av0[7]=a01.w;
    av0[8]=a02.x; av0[9]=a02.y; av0[10]=a02.z; av0[11]=a02.w;
    #pragma unroll
    for (int h = 0; h < NH; ++h) {
      acc[h][0] += av0[h] * xv0.x;
      acc[h][1] += av0[h] * xv0.y;
    }
  }
  unsigned* Ap = (unsigned*)(A + (long)wid * KDIM);
  #pragma unroll
  for (int h = 0; h < NH; ++h) {
    unsigned pv = (unsigned)f2bf(acc[h][0]) | ((unsigned)f2bf(acc[h][1]) << 16);
    Ap[h * (DHID / 2) + lane] = pv;
  }
}

// ---------------- weight repack: Wcat[c][h*128+k] = Wlin[h*128+c][k], bf16 ----------------

__global__ void prep_wcat_k(const float* __restrict__ Wlin, unsigned short* __restrict__ Wcat) {
  int t = blockIdx.x * blockDim.x + threadIdx.x;  // 128*1536 total
  int c = t / KDIM, f = t - c * KDIM;
  int h = f >> 7, k = f & (DHID - 1);
  Wcat[t] = f2bf(Wlin[((h << 7) + c) * DHID + k]);
}

// ---------------- GEMM: part[ks][m,c] = A[m, ks-half] . Wcat[c, ks-half] ----------------
// 64 rows x 128 cols per block (4 waves, each 64x32 = 4 m-frags x 2 n-frags),
// split-K 2 -> 626 blocks (~2.4 waves/SIMD). Plain f32 partial stores, no atomics.

__global__ __launch_bounds__(256) void gemm_k(
    const unsigned short* __restrict__ A, const unsigned short* __restrict__ B,
    float* __restrict__ part, int M) {
  int w = threadIdx.x >> 6, lane = threadIdx.x & 63;
  int lr = lane & 15, lq = lane >> 4;
  int m0 = blockIdx.x * 64, n0 = w * 32;
  int ks = blockIdx.y;
  if (m0 >= M) return;
  f32x4 acc[4][2];
  #pragma unroll
  for (int mf = 0; mf < 4; ++mf)
    #pragma unroll
    for (int nf = 0; nf < 2; ++nf) acc[mf][nf] = (f32x4){0.f, 0.f, 0.f, 0.f};
  const short* Ap = (const short*)A;
  const short* Bp = (const short*)B;
  long arow[4], brow[2];
  #pragma unroll
  for (int mf = 0; mf < 4; ++mf) arow[mf] = (long)(m0 + mf * 16 + lr) * KDIM + lq * 8;
  #pragma unroll
  for (int nf = 0; nf < 2; ++nf) brow[nf] = (long)(n0 + nf * 16 + lr) * KDIM + lq * 8;
  const int kbeg = ks * (KDIM / 2), kend = kbeg + (KDIM / 2);
  #pragma unroll 2
  for (int kk = kbeg; kk < kend; kk += 32) {
    short8 av[4], bv[2];
    #pragma unroll
    for (int mf = 0; mf < 4; ++mf) av[mf] = *(const short8*)(Ap + arow[mf] + kk);
    #pragma unroll
    for (int nf = 0; nf < 2; ++nf) bv[nf] = *(const short8*)(Bp + brow[nf] + kk);
    #pragma unroll
    for (int mf = 0; mf < 4; ++mf)
      #pragma unroll
      for (int nf = 0; nf < 2; ++nf)
        acc[mf][nf] = __builtin_amdgcn_mfma_f32_16x16x32_bf16(av[mf], bv[nf], acc[mf][nf], 0, 0, 0);
  }
  float* op = part + (long)ks * M * DHID;
  #pragma unroll
  for (int mf = 0; mf < 4; ++mf) {
    #pragma unroll
    for (int nf = 0; nf < 2; ++nf) {
      int c = n0 + nf * 16 + lr;
      int rowb = m0 + mf * 16 + lq * 4;
      #pragma unroll
      for (int r = 0; r < 4; ++r) {
        int row = rowb + r;
        if (row < M) op[(long)row * DHID + c] = acc[mf][nf][r];
      }
    }
  }
}

// ---------------- combine partials: out = part0 + part1 + bias (+relu). No atomics. ----------------

__global__ void combine_k(const float* __restrict__ part, const float* __restrict__ bias,
                          float* __restrict__ outp, int M, int relu) {
  int t = blockIdx.x * blockDim.x + threadIdx.x;
  int nvec = M * (DHID / 4);
  if (t >= nvec) return;
  long idx = (long)t * 4;
  int c = (t & 31) * 4;
  float4 p0 = *(const float4*)(part + idx);
  float4 p1 = *(const float4*)(part + (long)M * DHID + idx);
  float4 bc = *(const float4*)(bias + c);
  float4 v;
  v.x = p0.x + p1.x + bc.x;
  v.y = p0.y + p1.y + bc.y;
  v.z = p0.z + p1.z + bc.z;
  v.w = p0.w + p1.w + bc.w;
  if (relu) {
    v.x = fmaxf(v.x, 0.f); v.y = fmaxf(v.y, 0.f);
    v.z = fmaxf(v.z, 0.f); v.w = fmaxf(v.w, 0.f);
  }
  *(float4*)(outp + idx) = v;
}

// ---------------- BN stats: per-block register/LDS reduce, plain stores ----------------
// bnpart[bid][t]: t<128 -> sum of channel t; t>=128 -> sumsq of channel t-128.

__global__ __launch_bounds__(256) void bnstat_k(const float* __restrict__ buf,
                                                float* __restrict__ bnpart, int nvec) {
  int t = blockIdx.x * 256 + threadIdx.x;
  const int stride = NSTATB * 256;
  float s0=0,s1=0,s2=0,s3=0,q0=0,q1=0,q2=0,q3=0;
  for (int i = t; i < nvec; i += stride) {
    float4 v = *(const float4*)(buf + (long)i * 4);   // channel quad = (i&31)*4, loop-invariant
    s0 += v.x; s1 += v.y; s2 += v.z; s3 += v.w;
    q0 += v.x*v.x; q1 += v.y*v.y; q2 += v.z*v.z; q3 += v.w*v.w;
  }
  // lanes l and l^32 hold the same channel quad
  s0 += __shfl_xor(s0, 32); s1 += __shfl_xor(s1, 32);
  s2 += __shfl_xor(s2, 32); s3 += __shfl_xor(s3, 32);
  q0 += __shfl_xor(q0, 32); q1 += __shfl_xor(q1, 32);
  q2 += __shfl_xor(q2, 32); q3 += __shfl_xor(q3, 32);
  __shared__ float red[4][256];
  int w = threadIdx.x >> 6, lane = threadIdx.x & 63;
  if (lane < 32) {
    int cb = lane * 4;
    red[w][cb+0] = s0; red[w][cb+1] = s1; red[w][cb+2] = s2; red[w][cb+3] = s3;
    red[w][128+cb+0] = q0; red[w][128+cb+1] = q1; red[w][128+cb+2] = q2; red[w][128+cb+3] = q3;
  }
  __syncthreads();
  int tt = threadIdx.x;
  float p = red[0][tt] + red[1][tt] + red[2][tt] + red[3][tt];
  bnpart[blockIdx.x * 256 + tt] = p;
}

// ---------------- BatchNorm finalize + apply (in place) ----------------

__global__ void bnfin_k(const float* __restrict__ bnpart,
                        const float* __restrict__ g, const float* __restrict__ b,
                        float* __restrict__ sc, float* __restrict__ sh, float invn) {
  __shared__ float col[256];
  int t = threadIdx.x;
  float s = 0.f;
  #pragma unroll 8
  for (int bb = 0; bb < NSTATB; ++bb) s += bnpart[bb * 256 + t];
  col[t] = s;
  __syncthreads();
  if (t < DHID) {
    float m = col[t] * invn;
    float v = col[128 + t] * invn - m * m;
    float rs = rsqrtf(v + 1e-5f);
    float sg = g[t] * rs;
    sc[t] = sg;
    sh[t] = b[t] - m * sg;
  }
}

__global__ void bnapply_k(float* __restrict__ buf, const float* __restrict__ sc,
                          const float* __restrict__ sh, int nvec) {
  int i = blockIdx.x * blockDim.x + threadIdx.x;
  if (i >= nvec) return;
  long idx = (long)i * 4;
  int c = (int)(idx & (DHID - 1));
  float4 v = *(const float4*)(buf + idx);
  v.x = v.x * sc[c]     + sh[c];
  v.y = v.y * sc[c + 1] + sh[c + 1];
  v.z = v.z * sc[c + 2] + sh[c + 2];
  v.w = v.w * sc[c + 3] + sh[c + 3];
  *(float4*)(buf + idx) = v;
}

// ---------------- launch ----------------

extern "C" void kernel_launch(void* const* d_in, const int* in_sizes, int n_in,
                              void* d_out, int out_size, void* d_ws, size_t ws_size,
                              hipStream_t stream) {
  const float* x = (const float*)d_in[0];
  const int* ei = (const int*)d_in[1];
  const int N = in_sizes[0] / DHID;
  const int E0 = in_sizes[1] / 2;
  const int ET = E0 + N;
  const int* srcp = ei;
  const int* dstp = ei + E0;
  const float* Wlin[3] = {(const float*)d_in[2], (const float*)d_in[6], (const float*)d_in[10]};
  const float* Wu[3]   = {(const float*)d_in[3], (const float*)d_in[7], (const float*)d_in[11]};
  const float* cc[3]   = {(const float*)d_in[4], (const float*)d_in[8], (const float*)d_in[12]};
  const float* bb[3]   = {(const float*)d_in[5], (const float*)d_in[9], (const float*)d_in[13]};
  const float* bng[2]  = {(const float*)d_in[14], (const float*)d_in[16]};
  const float* bnb[2]  = {(const float*)d_in[15], (const float*)d_in[17]};

  const int MPAD = ((N + 63) / 64) * 64;

  // carve workspace
  size_t o = 0;
  char* base = (char*)d_ws;
  auto carve = [&](size_t bytes) -> char* {
    char* p = base + o;
    o += (bytes + 255) & ~(size_t)255;
    return p;
  };
  int* row_start = (int*)carve((size_t)(N + 1) * 4);
  int* cursor    = (int*)carve((size_t)N * 4);       // doubles as histogram
  int* srcs      = (int*)carve((size_t)ET * 4);
  int* dsts      = (int*)carve((size_t)ET * 4);
  float* u       = (float*)carve((size_t)N * NH * 4);
  float* bnpart  = (float*)carve((size_t)NSTATB * 256 * 4);
  float* bnsc    = (float*)carve((size_t)DHID * 4);
  float* bnsh    = (float*)carve((size_t)DHID * 4);
  unsigned short* Wcat = (unsigned short*)carve((size_t)DHID * KDIM * 2);
  // attS and split-K partials alias (disjoint in time within a layer)
  size_t attS_bytes = (size_t)ET * NH * 4;
  size_t part_bytes = (size_t)2 * N * DHID * 4;
  char* shared_rg = carve(attS_bytes > part_bytes ? attS_bytes : part_bytes);
  float* attS = (float*)shared_rg;
  float* partb = (float*)shared_rg;
  float* hA      = (float*)carve((size_t)N * DHID * 4);
  unsigned short* A = (unsigned short*)carve((size_t)MPAD * KDIM * 2);
  (void)ws_size; (void)n_in; (void)out_size;

  const int EB = (ET + 255) / 256;
  const int NW = (N + 3) / 4;       // 4 waves (nodes) per 256-thread block
  const int MB64 = (N + 63) / 64;
  const int AV = (N * DHID / 4 + 255) / 256;

  // sort edges by dst (once; dst list is layer-invariant)
  hipMemsetAsync(cursor, 0, (size_t)N * 4, stream);
  hist_k<<<EB, 256, 0, stream>>>(dstp, cursor, E0, ET);
  scan_k<<<1, 1024, 0, stream>>>(cursor, row_start, cursor, N, ET);
  scatter_k<<<EB, 256, 0, stream>>>(srcp, dstp, cursor, srcs, dsts, E0, ET);

  const float* hin = x;
  for (int li = 0; li < 3; ++li) {
    const bool last = (li == 2);
    u_k<<<NW, 256, 0, stream>>>(hin, Wu[li], u, N);
    att_k<<<EB, 256, 0, stream>>>(u, cc[li], srcs, dsts, row_start, attS, ET);
    edge_k<<<NW, 256, 0, stream>>>(hin, attS, srcs, row_start, A, N);
    prep_wcat_k<<<(DHID * KDIM) / 256, 256, 0, stream>>>(Wlin[li], Wcat);
    gemm_k<<<dim3(MB64, 2), 256, 0, stream>>>(A, Wcat, partb, N);
    float* outp = last ? (float*)d_out : hA;
    combine_k<<<AV, 256, 0, stream>>>(partb, bb[li], outp, N, last ? 0 : 1);
    if (!last) {
      bnstat_k<<<NSTATB, 256, 0, stream>>>(hA, bnpart, N * DHID / 4);
      bnfin_k<<<1, 256, 0, stream>>>(bnpart, bng[li], bnb[li], bnsc, bnsh, 1.f / (float)N);
      bnapply_k<<<AV, 256, 0, stream>>>(hA, bnsc, bnsh, N * DHID / 4);
      hin = hA;
    }
  }
}

// Round 6
// 543.072 us; speedup vs baseline: 1.2503x; 1.0416x over previous
//
#include <hip/hip_runtime.h>
#include <hip/hip_bf16.h>

#define DHID 128
#define NH 12
#define KDIM 1536   // NH * DHID
#define KSPLIT 3
#define KS (KDIM / KSPLIT)   // 512, 16 k-steps of 32
#define NSTATB 128  // bnstat partial blocks

typedef __attribute__((ext_vector_type(8))) short short8;
typedef __attribute__((ext_vector_type(4))) float f32x4;

static __device__ __forceinline__ unsigned short f2bf(float f) {
  __hip_bfloat16 h = __float2bfloat16(f);
  return __builtin_bit_cast(unsigned short, h);
}

// ---------------- sort (counting sort of edges by dst) ----------------

__global__ void hist_k(const int* __restrict__ dstp, int* __restrict__ cnt, int e0, int et) {
  int e = blockIdx.x * blockDim.x + threadIdx.x;
  if (e >= et) return;
  int d = (e < e0) ? dstp[e] : (e - e0);   // self-loop edges appended at the end
  atomicAdd(&cnt[d], 1);
}

// cnt and cursor may alias (in-place): each element is read before rewrite.
__global__ void scan_k(const int* __restrict__ cnt, int* __restrict__ row_start,
                       int* __restrict__ cursor, int n, int total) {
  __shared__ int part[1024];
  int t = threadIdx.x;
  const int CH = (n + 1023) >> 10;
  int base = t * CH;
  int s = 0;
  for (int j = 0; j < CH; ++j) { int i = base + j; if (i < n) s += cnt[i]; }
  part[t] = s;
  __syncthreads();
  for (int off = 1; off < 1024; off <<= 1) {
    int v = (t >= off) ? part[t - off] : 0;
    __syncthreads();
    part[t] += v;
    __syncthreads();
  }
  int run = (t == 0) ? 0 : part[t - 1];
  for (int j = 0; j < CH; ++j) {
    int i = base + j;
    if (i < n) {
      int c = cnt[i];              // read BEFORE cursor write (may alias)
      row_start[i] = run;
      cursor[i] = run;
      run += c;
    }
  }
  if (t == 0) row_start[n] = total;
}

__global__ void scatter_k(const int* __restrict__ srcp, const int* __restrict__ dstp,
                          int* __restrict__ cursor, int* __restrict__ srcs,
                          int* __restrict__ dsts, int e0, int et) {
  int e = blockIdx.x * blockDim.x + threadIdx.x;
  if (e >= et) return;
  int s = (e < e0) ? srcp[e] : (e - e0);
  int d = (e < e0) ? dstp[e] : (e - e0);
  int pos = atomicAdd(&cursor[d], 1);
  srcs[pos] = s;
  dsts[pos] = d;
}

// ---------------- per-node u = x . Wu[h] ----------------

__global__ void u_k(const float* __restrict__ x, const float* __restrict__ Wu,
                    float* __restrict__ u, int n) {
  int wid = (blockIdx.x * blockDim.x + threadIdx.x) >> 6;
  if (wid >= n) return;
  int lane = threadIdx.x & 63;
  float2 xv = *(const float2*)(x + (long)wid * DHID + 2 * lane);
  #pragma unroll
  for (int h = 0; h < NH; ++h) {
    float2 wv = *(const float2*)(Wu + h * DHID + 2 * lane);
    float p = xv.x * wv.x + xv.y * wv.y;
    p += __shfl_xor(p, 1);  p += __shfl_xor(p, 2);  p += __shfl_xor(p, 4);
    p += __shfl_xor(p, 8);  p += __shfl_xor(p, 16); p += __shfl_xor(p, 32);
    if (lane == 0) u[wid * NH + h] = p;
  }
}

// ---------------- per-edge attention (thread per edge, dst-sorted order) ----------------
// attS[j][h] = softmax_h(u[dst]-u[src]+c) / deg(dst)

__global__ void att_k(const float* __restrict__ u, const float* __restrict__ cvec,
                      const int* __restrict__ srcs, const int* __restrict__ dsts,
                      const int* __restrict__ row_start, float* __restrict__ attS, int et) {
  int j = blockIdx.x * blockDim.x + threadIdx.x;
  if (j >= et) return;
  int s = srcs[j], d = dsts[j];
  const float4* ud = (const float4*)(u + (long)d * NH);
  const float4* us = (const float4*)(u + (long)s * NH);
  const float4* cp = (const float4*)cvec;
  float w[NH];
  #pragma unroll
  for (int q = 0; q < 3; ++q) {
    float4 a = ud[q], b = us[q], c = cp[q];
    w[4*q+0] = a.x - b.x + c.x;
    w[4*q+1] = a.y - b.y + c.y;
    w[4*q+2] = a.z - b.z + c.z;
    w[4*q+3] = a.w - b.w + c.w;
  }
  float m = w[0];
  #pragma unroll
  for (int h = 1; h < NH; ++h) m = fmaxf(m, w[h]);
  float ssum = 0.f;
  #pragma unroll
  for (int h = 0; h < NH; ++h) { w[h] = __expf(w[h] - m); ssum += w[h]; }
  float deg = (float)(row_start[d + 1] - row_start[d]);
  float inv = 1.f / (ssum * deg);
  float4* op = (float4*)(attS + (long)j * NH);
  #pragma unroll
  for (int q = 0; q < 3; ++q) {
    float4 v;
    v.x = w[4*q+0] * inv; v.y = w[4*q+1] * inv;
    v.z = w[4*q+2] * inv; v.w = w[4*q+3] * inv;
    op[q] = v;
  }
}

// ---------------- edge aggregation: A[n,h,:] = sum_j attS[j,h] * x[srcs[j]] ----------------
// unroll 4: 4 gathers + 12 attS quads in flight per iteration.

__global__ void edge_k(const float* __restrict__ x, const float* __restrict__ attS,
                       const int* __restrict__ srcs, const int* __restrict__ row_start,
                       unsigned short* __restrict__ A, int n) {
  int wid = __builtin_amdgcn_readfirstlane((int)((blockIdx.x * blockDim.x + threadIdx.x) >> 6));
  if (wid >= n) return;
  int lane = threadIdx.x & 63;
  float acc[NH][2];
  #pragma unroll
  for (int h = 0; h < NH; ++h) { acc[h][0] = 0.f; acc[h][1] = 0.f; }
  int beg = row_start[wid], end = row_start[wid + 1];
  int j = beg;
  for (; j + 3 < end; j += 4) {
    int sx[4];
    #pragma unroll
    for (int i = 0; i < 4; ++i) sx[i] = srcs[j + i];
    float2 xv[4];
    #pragma unroll
    for (int i = 0; i < 4; ++i)
      xv[i] = *(const float2*)(x + (long)sx[i] * DHID + 2 * lane);
    const float4* ap = (const float4*)(attS + (long)j * NH);
    float4 aq[4][3];
    #pragma unroll
    for (int i = 0; i < 4; ++i) {
      aq[i][0] = ap[i * 3 + 0];
      aq[i][1] = ap[i * 3 + 1];
      aq[i][2] = ap[i * 3 + 2];
    }
    #pragma unroll
    for (int i = 0; i < 4; ++i) {
      float av[NH];
      av[0]=aq[i][0].x; av[1]=aq[i][0].y; av[2] =aq[i][0].z; av[3] =aq[i][0].w;
      av[4]=aq[i][1].x; av[5]=aq[i][1].y; av[6] =aq[i][1].z; av[7] =aq[i][1].w;
      av[8]=aq[i][2].x; av[9]=aq[i][2].y; av[10]=aq[i][2].z; av[11]=aq[i][2].w;
      #pragma unroll
      for (int h = 0; h < NH; ++h) {
        acc[h][0] += av[h] * xv[i].x;
        acc[h][1] += av[h] * xv[i].y;
      }
    }
  }
  for (; j < end; ++j) {
    int s0 = srcs[j];
    float2 xv0 = *(const float2*)(x + (long)s0 * DHID + 2 * lane);
    const float4* a0p = (const float4*)(attS + (long)j * NH);
    float4 a00 = a0p[0], a01 = a0p[1], a02 = a0p[2];
    float av0[NH];
    av0[0]=a00.x; av0[1]=a00.y; av0[2]=a00.z;  av0[3]=a00.w;
    av0[4]=a01.x; av0[5]=a01.y; av0[6]=a01.z;  av0[7]=a01.w;
    av0[8]=a02.x; av0[9]=a02.y; av0[10]=a02.z; av0[11]=a02.w;
    #pragma unroll
    for (int h = 0; h < NH; ++h) {
      acc[h][0] += av0[h] * xv0.x;
      acc[h][1] += av0[h] * xv0.y;
    }
  }
  unsigned* Ap = (unsigned*)(A + (long)wid * KDIM);
  #pragma unroll
  for (int h = 0; h < NH; ++h) {
    unsigned pv = (unsigned)f2bf(acc[h][0]) | ((unsigned)f2bf(acc[h][1]) << 16);
    Ap[h * (DHID / 2) + lane] = pv;
  }
}

// ---------------- weight repack: Wcat[c][h*128+k] = Wlin[h*128+c][k], bf16 ----------------

__global__ void prep_wcat_k(const float* __restrict__ Wlin, unsigned short* __restrict__ Wcat) {
  int t = blockIdx.x * blockDim.x + threadIdx.x;  // 128*1536 total
  int c = t / KDIM, f = t - c * KDIM;
  int h = f >> 7, k = f & (DHID - 1);
  Wcat[t] = f2bf(Wlin[((h << 7) + c) * DHID + k]);
}

// ---------------- GEMM: split-K 3; slice 0 -> outp, slices 1,2 -> part ----------------
// 64 rows x 128 cols per block (4 waves, each 64x32 = 4 m-frags x 2 n-frags),
// grid (ceil(M/64), 3) = 939 blocks (~3.7 waves/SIMD). Plain f32 stores, no atomics.

__global__ __launch_bounds__(256) void gemm_k(
    const unsigned short* __restrict__ A, const unsigned short* __restrict__ B,
    float* __restrict__ part, float* __restrict__ outp, int M) {
  int w = threadIdx.x >> 6, lane = threadIdx.x & 63;
  int lr = lane & 15, lq = lane >> 4;
  int m0 = blockIdx.x * 64, n0 = w * 32;
  int ks = blockIdx.y;
  if (m0 >= M) return;
  f32x4 acc[4][2];
  #pragma unroll
  for (int mf = 0; mf < 4; ++mf)
    #pragma unroll
    for (int nf = 0; nf < 2; ++nf) acc[mf][nf] = (f32x4){0.f, 0.f, 0.f, 0.f};
  const short* Ap = (const short*)A;
  const short* Bp = (const short*)B;
  long arow[4], brow[2];
  #pragma unroll
  for (int mf = 0; mf < 4; ++mf) arow[mf] = (long)(m0 + mf * 16 + lr) * KDIM + lq * 8;
  #pragma unroll
  for (int nf = 0; nf < 2; ++nf) brow[nf] = (long)(n0 + nf * 16 + lr) * KDIM + lq * 8;
  const int kbeg = ks * KS, kend = kbeg + KS;
  #pragma unroll 2
  for (int kk = kbeg; kk < kend; kk += 32) {
    short8 av[4], bv[2];
    #pragma unroll
    for (int mf = 0; mf < 4; ++mf) av[mf] = *(const short8*)(Ap + arow[mf] + kk);
    #pragma unroll
    for (int nf = 0; nf < 2; ++nf) bv[nf] = *(const short8*)(Bp + brow[nf] + kk);
    #pragma unroll
    for (int mf = 0; mf < 4; ++mf)
      #pragma unroll
      for (int nf = 0; nf < 2; ++nf)
        acc[mf][nf] = __builtin_amdgcn_mfma_f32_16x16x32_bf16(av[mf], bv[nf], acc[mf][nf], 0, 0, 0);
  }
  float* op = (ks == 0) ? outp : (part + (long)(ks - 1) * M * DHID);
  #pragma unroll
  for (int mf = 0; mf < 4; ++mf) {
    #pragma unroll
    for (int nf = 0; nf < 2; ++nf) {
      int c = n0 + nf * 16 + lr;
      int rowb = m0 + mf * 16 + lq * 4;
      #pragma unroll
      for (int r = 0; r < 4; ++r) {
        int row = rowb + r;
        if (row < M) op[(long)row * DHID + c] = acc[mf][nf][r];
      }
    }
  }
}

// ---------------- combine: outp += part1 + part2 + bias (+relu). No atomics. ----------------

__global__ void combine_k(const float* __restrict__ part, const float* __restrict__ bias,
                          float* __restrict__ outp, int M, int relu) {
  int t = blockIdx.x * blockDim.x + threadIdx.x;
  int nvec = M * (DHID / 4);
  if (t >= nvec) return;
  long idx = (long)t * 4;
  int c = (t & 31) * 4;
  float4 p0 = *(const float4*)(outp + idx);
  float4 p1 = *(const float4*)(part + idx);
  float4 p2 = *(const float4*)(part + (long)M * DHID + idx);
  float4 bc = *(const float4*)(bias + c);
  float4 v;
  v.x = p0.x + p1.x + p2.x + bc.x;
  v.y = p0.y + p1.y + p2.y + bc.y;
  v.z = p0.z + p1.z + p2.z + bc.z;
  v.w = p0.w + p1.w + p2.w + bc.w;
  if (relu) {
    v.x = fmaxf(v.x, 0.f); v.y = fmaxf(v.y, 0.f);
    v.z = fmaxf(v.z, 0.f); v.w = fmaxf(v.w, 0.f);
  }
  *(float4*)(outp + idx) = v;
}

// ---------------- BN stats: per-block register/LDS reduce, plain stores ----------------
// bnpart[bid][t]: t<128 -> sum of channel t; t>=128 -> sumsq of channel t-128.

__global__ __launch_bounds__(256) void bnstat_k(const float* __restrict__ buf,
                                                float* __restrict__ bnpart, int nvec) {
  int t = blockIdx.x * 256 + threadIdx.x;
  const int stride = NSTATB * 256;
  float s0=0,s1=0,s2=0,s3=0,q0=0,q1=0,q2=0,q3=0;
  for (int i = t; i < nvec; i += stride) {
    float4 v = *(const float4*)(buf + (long)i * 4);   // channel quad = (i&31)*4, loop-invariant
    s0 += v.x; s1 += v.y; s2 += v.z; s3 += v.w;
    q0 += v.x*v.x; q1 += v.y*v.y; q2 += v.z*v.z; q3 += v.w*v.w;
  }
  // lanes l and l^32 hold the same channel quad
  s0 += __shfl_xor(s0, 32); s1 += __shfl_xor(s1, 32);
  s2 += __shfl_xor(s2, 32); s3 += __shfl_xor(s3, 32);
  q0 += __shfl_xor(q0, 32); q1 += __shfl_xor(q1, 32);
  q2 += __shfl_xor(q2, 32); q3 += __shfl_xor(q3, 32);
  __shared__ float red[4][256];
  int w = threadIdx.x >> 6, lane = threadIdx.x & 63;
  if (lane < 32) {
    int cb = lane * 4;
    red[w][cb+0] = s0; red[w][cb+1] = s1; red[w][cb+2] = s2; red[w][cb+3] = s3;
    red[w][128+cb+0] = q0; red[w][128+cb+1] = q1; red[w][128+cb+2] = q2; red[w][128+cb+3] = q3;
  }
  __syncthreads();
  int tt = threadIdx.x;
  float p = red[0][tt] + red[1][tt] + red[2][tt] + red[3][tt];
  bnpart[blockIdx.x * 256 + tt] = p;
}

// ---------------- BatchNorm finalize + apply (in place) ----------------

__global__ void bnfin_k(const float* __restrict__ bnpart,
                        const float* __restrict__ g, const float* __restrict__ b,
                        float* __restrict__ sc, float* __restrict__ sh, float invn) {
  __shared__ float col[256];
  int t = threadIdx.x;
  float s = 0.f;
  #pragma unroll 8
  for (int bb = 0; bb < NSTATB; ++bb) s += bnpart[bb * 256 + t];
  col[t] = s;
  __syncthreads();
  if (t < DHID) {
    float m = col[t] * invn;
    float v = col[128 + t] * invn - m * m;
    float rs = rsqrtf(v + 1e-5f);
    float sg = g[t] * rs;
    sc[t] = sg;
    sh[t] = b[t] - m * sg;
  }
}

__global__ void bnapply_k(float* __restrict__ buf, const float* __restrict__ sc,
                          const float* __restrict__ sh, int nvec) {
  int i = blockIdx.x * blockDim.x + threadIdx.x;
  if (i >= nvec) return;
  long idx = (long)i * 4;
  int c = (int)(idx & (DHID - 1));
  float4 v = *(const float4*)(buf + idx);
  v.x = v.x * sc[c]     + sh[c];
  v.y = v.y * sc[c + 1] + sh[c + 1];
  v.z = v.z * sc[c + 2] + sh[c + 2];
  v.w = v.w * sc[c + 3] + sh[c + 3];
  *(float4*)(buf + idx) = v;
}

// ---------------- launch ----------------

extern "C" void kernel_launch(void* const* d_in, const int* in_sizes, int n_in,
                              void* d_out, int out_size, void* d_ws, size_t ws_size,
                              hipStream_t stream) {
  const float* x = (const float*)d_in[0];
  const int* ei = (const int*)d_in[1];
  const int N = in_sizes[0] / DHID;
  const int E0 = in_sizes[1] / 2;
  const int ET = E0 + N;
  const int* srcp = ei;
  const int* dstp = ei + E0;
  const float* Wlin[3] = {(const float*)d_in[2], (const float*)d_in[6], (const float*)d_in[10]};
  const float* Wu[3]   = {(const float*)d_in[3], (const float*)d_in[7], (const float*)d_in[11]};
  const float* cc[3]   = {(const float*)d_in[4], (const float*)d_in[8], (const float*)d_in[12]};
  const float* bb[3]   = {(const float*)d_in[5], (const float*)d_in[9], (const float*)d_in[13]};
  const float* bng[2]  = {(const float*)d_in[14], (const float*)d_in[16]};
  const float* bnb[2]  = {(const float*)d_in[15], (const float*)d_in[17]};

  const int MPAD = ((N + 63) / 64) * 64;

  // carve workspace
  size_t o = 0;
  char* base = (char*)d_ws;
  auto carve = [&](size_t bytes) -> char* {
    char* p = base + o;
    o += (bytes + 255) & ~(size_t)255;
    return p;
  };
  int* row_start = (int*)carve((size_t)(N + 1) * 4);
  int* cursor    = (int*)carve((size_t)N * 4);       // doubles as histogram
  int* srcs      = (int*)carve((size_t)ET * 4);
  int* dsts      = (int*)carve((size_t)ET * 4);
  float* u       = (float*)carve((size_t)N * NH * 4);
  float* bnpart  = (float*)carve((size_t)NSTATB * 256 * 4);
  float* bnsc    = (float*)carve((size_t)DHID * 4);
  float* bnsh    = (float*)carve((size_t)DHID * 4);
  unsigned short* Wcat = (unsigned short*)carve((size_t)DHID * KDIM * 2);
  // attS and split-K partials (2 slices) alias (disjoint in time within a layer)
  size_t attS_bytes = (size_t)ET * NH * 4;
  size_t part_bytes = (size_t)(KSPLIT - 1) * N * DHID * 4;
  char* shared_rg = carve(attS_bytes > part_bytes ? attS_bytes : part_bytes);
  float* attS = (float*)shared_rg;
  float* partb = (float*)shared_rg;
  float* hA      = (float*)carve((size_t)N * DHID * 4);
  unsigned short* A = (unsigned short*)carve((size_t)MPAD * KDIM * 2);
  (void)ws_size; (void)n_in; (void)out_size;

  const int EB = (ET + 255) / 256;
  const int NW = (N + 3) / 4;       // 4 waves (nodes) per 256-thread block
  const int MB64 = (N + 63) / 64;
  const int AV = (N * DHID / 4 + 255) / 256;

  // sort edges by dst (once; dst list is layer-invariant)
  hipMemsetAsync(cursor, 0, (size_t)N * 4, stream);
  hist_k<<<EB, 256, 0, stream>>>(dstp, cursor, E0, ET);
  scan_k<<<1, 1024, 0, stream>>>(cursor, row_start, cursor, N, ET);
  scatter_k<<<EB, 256, 0, stream>>>(srcp, dstp, cursor, srcs, dsts, E0, ET);

  const float* hin = x;
  for (int li = 0; li < 3; ++li) {
    const bool last = (li == 2);
    u_k<<<NW, 256, 0, stream>>>(hin, Wu[li], u, N);
    att_k<<<EB, 256, 0, stream>>>(u, cc[li], srcs, dsts, row_start, attS, ET);
    edge_k<<<NW, 256, 0, stream>>>(hin, attS, srcs, row_start, A, N);
    prep_wcat_k<<<(DHID * KDIM) / 256, 256, 0, stream>>>(Wlin[li], Wcat);
    float* outp = last ? (float*)d_out : hA;
    gemm_k<<<dim3(MB64, KSPLIT), 256, 0, stream>>>(A, Wcat, partb, outp, N);
    combine_k<<<AV, 256, 0, stream>>>(partb, bb[li], outp, N, last ? 0 : 1);
    if (!last) {
      bnstat_k<<<NSTATB, 256, 0, stream>>>(hA, bnpart, N * DHID / 4);
      bnfin_k<<<1, 256, 0, stream>>>(bnpart, bng[li], bnb[li], bnsc, bnsh, 1.f / (float)N);
      bnapply_k<<<AV, 256, 0, stream>>>(hA, bnsc, bnsh, N * DHID / 4);
      hin = hA;
    }
  }
}